// Round 3
// baseline (193.192 us; speedup 1.0000x reference)
//
#include <hip/hip_runtime.h>

// KGAN forward loss on MI355X.
// R3: 512-thread blocks (8 waves, 2 groups/wave -> 2x chain ILP),
// all-VALU reductions (DPP + permlane16/32_swap, no LDS-pipe ops),
// explicit double-buffered register prefetch of h/t gathers.

#define BATCH 1024
#define G     16
#define NMEM  32
#define DIM   64
#define NREL  17

// ---- cross-lane helpers (all VALU pipe) ------------------------------------
// quad_perm xor1 = 0xB1, xor2 = 0x4E; row_ror:4 = 0x124, row_ror:8 = 0x128.
template<int CTRL>
__device__ __forceinline__ float dpp_add(float x) {
    int y = __builtin_amdgcn_update_dpp(0, __float_as_int(x), CTRL, 0xF, 0xF, true);
    return x + __int_as_float(y);
}
// sum within each 32-lane half; all lanes get their half's sum
__device__ __forceinline__ float red32p(float v) {
    v = dpp_add<0xB1>(v);
    v = dpp_add<0x4E>(v);
    v = dpp_add<0x124>(v);
    v = dpp_add<0x128>(v);
    float a = v, b = v;
    asm("v_permlane16_swap_b32 %0, %1" : "+v"(a), "+v"(b));
    return a + b;
}
// sum across all 64 lanes, result in every lane
__device__ __forceinline__ float red64p(float v) {
    v = red32p(v);
    float a = v, b = v;
    asm("v_permlane32_swap_b32 %0, %1" : "+v"(a), "+v"(b));
    return a + b;
}

// ws layout: acc double[4] at offset 0; u float[2*64] at offset 64.
__global__ void kgan_prep(const float* __restrict__ attn_w1,
                          const float* __restrict__ attn_w2,
                          float* __restrict__ u, double* __restrict__ acc) {
    int t = threadIdx.x;            // 0..127
    if (t < 4) acc[t] = 0.0;
    int hop = t >> 6, d = t & 63;
    float s = 0.f;
#pragma unroll
    for (int e = 0; e < DIM; ++e)
        s = fmaf(attn_w1[(hop * DIM + d) * DIM + e], attn_w2[hop * DIM + e], s);
    u[t] = s;
}

// prefetch one batch of 2 m's for both groups: indices (scalar loads) + gathers
#define PREF(IH, IT, IR, HV, TV, M0)                                     \
    _Pragma("unroll") for (int grp = 0; grp < 2; ++grp) {                \
        _Pragma("unroll") for (int j = 0; j < 2; ++j) {                  \
            IH[grp][j] = mem_h[base[grp] + (M0) + j];                    \
            IT[grp][j] = mem_t[base[grp] + (M0) + j];                    \
            IR[grp][j] = mem_r[base[grp] + (M0) + j];                    \
            HV[grp][j] = ent[(size_t)IH[grp][j] * DIM + lane];           \
            TV[grp][j] = ent[(size_t)IT[grp][j] * DIM + lane];           \
        }                                                                \
    }

#define COMP(IR, HV, TV)                                                 \
    _Pragma("unroll") for (int grp = 0; grp < 2; ++grp) {                \
        _Pragma("unroll") for (int j = 0; j < 2; ++j) {                  \
            const int    ir  = IR[grp][j];                               \
            const float  h   = HV[grp][j];                               \
            const float  t   = TV[grp][j];                               \
            const float2 rr2 = rv_rs[ir];                                \
            const float  r   = rel_lds[ir][lane];                        \
            float e  = __expf(h * rr2.x);                                \
            float de = red32p(e);                                        \
            float rt = red64p(r * t);                                    \
            o_d[grp] = fmaf(t, e * __builtin_amdgcn_rcpf(de), o_d[grp]); \
            float z  = h * rt;                                           \
            kge_acc += __builtin_amdgcn_rcpf(1.f + __expf(-z));          \
            l2_acc   = fmaf(h, h, l2_acc);                               \
            l2_acc   = fmaf(t, t, l2_acc);                               \
            l2r_acc += rr2.y;                                            \
        }                                                                \
    }

__launch_bounds__(512, 8)
__global__ void kgan_main(const int* __restrict__ pos_items,
                          const int* __restrict__ neg_items,
                          const int* __restrict__ mem_h,
                          const int* __restrict__ mem_r,
                          const int* __restrict__ mem_t,
                          const float* __restrict__ ent,
                          const float* __restrict__ rel,
                          const float* __restrict__ Tm,
                          const float* __restrict__ u,
                          double* __restrict__ acc) {
    const int b    = blockIdx.x;
    const int tid  = threadIdx.x;
    const int lane = tid & 63;
    const int wid  = __builtin_amdgcn_readfirstlane(tid >> 6);  // 0..7
    const int g0   = wid;          // groups owned by this wave
    const int g1   = wid + 8;

    __shared__ float  rel_lds[NREL][DIM];
    __shared__ float2 rv_rs[NREL];        // (rdotv, rsq)
    __shared__ float  a_lds[G];
    __shared__ float  o_lds[G][DIM];
    __shared__ float  red_k[8];
    __shared__ float  red_l[8];
    __shared__ float  y_lds[DIM];

    for (int i = tid; i < NREL * DIM; i += 512)
        ((float*)rel_lds)[i] = rel[i];
    const float v = ent[(size_t)pos_items[b] * DIM + lane];
    __syncthreads();

    // per-block precompute: rdotv[r] = dot(rel_r, v); rsq[r] = ||rel_r||^2
    for (int rr = wid; rr < NREL; rr += 8) {
        float rd = rel_lds[rr][lane];
        float s1 = red64p(rd * v);
        float s2 = red64p(rd * rd);
        if (lane == 0) rv_rs[rr] = make_float2(s1, s2);
    }
    __syncthreads();

    float kge_acc = 0.f, l2_acc = 0.f, l2r_acc = 0.f;
    float y0 = 0.f;   // wave 0: y_d = sum_hop o_h
    float x1 = 0.f;   // wave 0: v + o_h(last hop)

#pragma unroll 1
    for (int hop = 0; hop < 2; ++hop) {
        int base[2];
        base[0] = ((hop * BATCH + b) * G + g0) * NMEM;
        base[1] = base[0] + 8 * NMEM;

        float o_d[2] = {0.f, 0.f};
        int   ih0[2][2], it0[2][2], ir0[2][2];
        int   ih1[2][2], it1[2][2], ir1[2][2];
        float hv0[2][2], tv0[2][2], hv1[2][2], tv1[2][2];

        PREF(ih0, it0, ir0, hv0, tv0, 0);
#pragma unroll 1
        for (int mbp = 0; mbp < 8; ++mbp) {
            const int m1 = mbp * 4 + 2;                  // buf1's batch
            PREF(ih1, it1, ir1, hv1, tv1, m1);
            COMP(ir0, hv0, tv0);
            if (mbp < 7) { PREF(ih0, it0, ir0, hv0, tv0, m1 + 2); }
            COMP(ir1, hv1, tv1);
        }

        // attention logits: a_g = relu(dot(o_g, u_hop))
        const float uh = u[hop * DIM + lane];
        float a0 = fmaxf(red64p(o_d[0] * uh), 0.f);
        float a1 = fmaxf(red64p(o_d[1] * uh), 0.f);
        if (lane == 0) { a_lds[g0] = a0; a_lds[g1] = a1; }
        o_lds[g0][lane] = o_d[0];
        o_lds[g1][lane] = o_d[1];
        __syncthreads();

        if (wid == 0) {
            float amax = -1e30f;
#pragma unroll
            for (int gg = 0; gg < G; ++gg) amax = fmaxf(amax, a_lds[gg]);
            float wexp[G]; float wsum = 0.f;
#pragma unroll
            for (int gg = 0; gg < G; ++gg) { wexp[gg] = __expf(a_lds[gg] - amax); wsum += wexp[gg]; }
            float inv = 1.f / wsum;
            float oh = 0.f;
#pragma unroll
            for (int gg = 0; gg < G; ++gg) oh = fmaf(o_lds[gg][lane], wexp[gg] * inv, oh);
            y0 += oh;
            if (hop == 1) x1 = v + oh;
        }
        __syncthreads();   // before next hop overwrites a_lds / o_lds
    }

    // block-level scalar reductions
    float kk = red64p(kge_acc);
    float ll = red64p(l2_acc);
    if (lane == 0) { red_k[wid] = kk; red_l[wid] = ll + l2r_acc; }
    if (wid == 0) y_lds[lane] = y0;
    __syncthreads();

    if (tid == 0) {
        float sk = 0.f, sl = 0.f;
#pragma unroll
        for (int gg = 0; gg < 8; ++gg) { sk += red_k[gg]; sl += red_l[gg]; }
        atomicAdd(&acc[1], (double)sk);
        atomicAdd(&acc[2], (double)sl);
    }

    if (wid == 0) {
        // z_e = sum_d Tm[e][d] * y[d]; score = dot(x1, Tm @ y)
        float z = 0.f;
#pragma unroll
        for (int e = 0; e < DIM; ++e) z = fmaf(Tm[lane * DIM + e], y_lds[e], z);
        float score = red64p(x1 * z);
        float nv    = ent[(size_t)neg_items[b] * DIM + lane];
        float nsc   = red64p(nv * y0);
        if (lane == 0) {
            float diff = score - nsc;
            float ls = fminf(diff, 0.f) - log1pf(__expf(-fabsf(diff)));
            atomicAdd(&acc[0], (double)ls);
        }
    }
}

__global__ void kgan_finalize(const double* __restrict__ acc, float* __restrict__ out) {
    double mf  = -acc[0] / (double)BATCH;
    double kge = acc[1] / ((double)BATCH * G * NMEM * DIM);   // sum of per-hop means
    double l2  = acc[2];
    out[0] = (float)(mf - 0.01 * kge + 1e-5 * l2);
}

extern "C" void kernel_launch(void* const* d_in, const int* in_sizes, int n_in,
                              void* d_out, int out_size, void* d_ws, size_t ws_size,
                              hipStream_t stream) {
    const int*   pos_items = (const int*)d_in[0];
    const int*   neg_items = (const int*)d_in[1];
    const int*   mem_h     = (const int*)d_in[2];
    const int*   mem_r     = (const int*)d_in[3];
    const int*   mem_t     = (const int*)d_in[4];
    const float* ent       = (const float*)d_in[5];
    const float* rel       = (const float*)d_in[6];
    const float* Tm        = (const float*)d_in[7];
    const float* attn_w1   = (const float*)d_in[8];
    const float* attn_w2   = (const float*)d_in[9];

    double* acc = (double*)d_ws;                     // 4 doubles
    float*  u   = (float*)((char*)d_ws + 64);        // 2*64 floats

    kgan_prep<<<1, 128, 0, stream>>>(attn_w1, attn_w2, u, acc);
    kgan_main<<<BATCH, 512, 0, stream>>>(pos_items, neg_items, mem_h, mem_r, mem_t,
                                         ent, rel, Tm, u, acc);
    kgan_finalize<<<1, 1, 0, stream>>>(acc, (float*)d_out);
}

// Round 4
// 133.338 us; speedup vs baseline: 1.4489x; 1.4489x over previous
//
#include <hip/hip_runtime.h>

// KGAN forward loss on MI355X.
// R4: all index loads hoisted to kernel start (lane-vector loads) +
// v_readlane broadcast in the m-loop -> only gather latency remains in-loop;
// compiler-scheduled unroll-8 pipeline; all-VALU DPP+permlane reductions.

#define BATCH 1024
#define G     16
#define NMEM  32
#define DIM   64
#define NREL  17

// ---- cross-lane helpers (all VALU pipe) ------------------------------------
template<int CTRL>
__device__ __forceinline__ float dpp_add(float x) {
    int y = __builtin_amdgcn_update_dpp(0, __float_as_int(x), CTRL, 0xF, 0xF, true);
    return x + __int_as_float(y);
}
// sum within each 32-lane half; all lanes get their half's sum
__device__ __forceinline__ float red32p(float v) {
    v = dpp_add<0xB1>(v);
    v = dpp_add<0x4E>(v);
    v = dpp_add<0x124>(v);
    v = dpp_add<0x128>(v);
    float a = v, b = v;
    asm("v_permlane16_swap_b32 %0, %1" : "+v"(a), "+v"(b));
    return a + b;
}
// sum across all 64 lanes, result in every lane
__device__ __forceinline__ float red64p(float v) {
    v = red32p(v);
    float a = v, b = v;
    asm("v_permlane32_swap_b32 %0, %1" : "+v"(a), "+v"(b));
    return a + b;
}

// ws layout: acc double[4] at offset 0; u float[2*64] at offset 64.
__global__ void kgan_prep(const float* __restrict__ attn_w1,
                          const float* __restrict__ attn_w2,
                          float* __restrict__ u, double* __restrict__ acc) {
    int t = threadIdx.x;            // 0..127
    if (t < 4) acc[t] = 0.0;
    int hop = t >> 6, d = t & 63;
    float s = 0.f;
#pragma unroll
    for (int e = 0; e < DIM; ++e)
        s = fmaf(attn_w1[(hop * DIM + d) * DIM + e], attn_w2[hop * DIM + e], s);
    u[t] = s;
}

__launch_bounds__(512, 8)
__global__ void kgan_main(const int* __restrict__ pos_items,
                          const int* __restrict__ neg_items,
                          const int* __restrict__ mem_h,
                          const int* __restrict__ mem_r,
                          const int* __restrict__ mem_t,
                          const float* __restrict__ ent,
                          const float* __restrict__ rel,
                          const float* __restrict__ Tm,
                          const float* __restrict__ u,
                          double* __restrict__ acc) {
    const int b    = blockIdx.x;
    const int tid  = threadIdx.x;
    const int lane = tid & 63;
    const int wid  = __builtin_amdgcn_readfirstlane(tid >> 6);  // 0..7
    const int g0   = wid;
    const int g1   = wid + 8;

    __shared__ float  rel_lds[NREL][DIM];
    __shared__ float2 rv_rs[NREL];        // (rdotv, rsq)
    __shared__ float  a_lds[G];
    __shared__ float  o_lds[G][DIM];
    __shared__ float  red_k[8];
    __shared__ float  red_l[8];
    __shared__ float  y_lds[DIM];

    // ---- hoisted index vector loads: both hops, both groups ----------------
    // lanes 0..31 carry h-indices (m = lane), lanes 32..63 carry t-indices.
    const int  mlane = lane & 31;
    const bool lo    = lane < 32;
    const int bA0 = ((0 * BATCH + b) * G + g0) * NMEM;
    const int bB0 = bA0 + 8 * NMEM;
    const int bA1 = ((1 * BATCH + b) * G + g0) * NMEM;
    const int bB1 = bA1 + 8 * NMEM;
    const int iA0 = lo ? mem_h[bA0 + mlane] : mem_t[bA0 + mlane];
    const int iB0 = lo ? mem_h[bB0 + mlane] : mem_t[bB0 + mlane];
    const int iR0 = lo ? mem_r[bA0 + mlane] : mem_r[bB0 + mlane];
    const int iA1 = lo ? mem_h[bA1 + mlane] : mem_t[bA1 + mlane];
    const int iB1 = lo ? mem_h[bB1 + mlane] : mem_t[bB1 + mlane];
    const int iR1 = lo ? mem_r[bA1 + mlane] : mem_r[bB1 + mlane];

    // stage relation table
    for (int i = tid; i < NREL * DIM; i += 512)
        ((float*)rel_lds)[i] = rel[i];
    const float v = ent[(size_t)pos_items[b] * DIM + lane];
    __syncthreads();

    // per-block precompute: rdotv[r] = dot(rel_r, v); rsq[r] = ||rel_r||^2
    for (int rr = wid; rr < NREL; rr += 8) {
        float rd = rel_lds[rr][lane];
        float s1 = red64p(rd * v);
        float s2 = red64p(rd * rd);
        if (lane == 0) rv_rs[rr] = make_float2(s1, s2);
    }
    __syncthreads();

    float kge_acc = 0.f, l2_acc = 0.f, l2r_acc = 0.f;
    float y0 = 0.f;   // wave 0: y_d = sum_hop o_h
    float x1 = 0.f;   // wave 0: v + o_h(last hop)

#pragma unroll
    for (int hop = 0; hop < 2; ++hop) {
        const int iA = hop ? iA1 : iA0;
        const int iB = hop ? iB1 : iB0;
        const int iR = hop ? iR1 : iR0;

        float o0 = 0.f, o1 = 0.f;
#pragma unroll 8
        for (int m = 0; m < NMEM; ++m) {
            const int ihA = __builtin_amdgcn_readlane(iA, m);
            const int itA = __builtin_amdgcn_readlane(iA, m + 32);
            const int irA = __builtin_amdgcn_readlane(iR, m);
            const int ihB = __builtin_amdgcn_readlane(iB, m);
            const int itB = __builtin_amdgcn_readlane(iB, m + 32);
            const int irB = __builtin_amdgcn_readlane(iR, m + 32);

            const float  hA = ent[(size_t)ihA * DIM + lane];
            const float  tA = ent[(size_t)itA * DIM + lane];
            const float  hB = ent[(size_t)ihB * DIM + lane];
            const float  tB = ent[(size_t)itB * DIM + lane];
            const float  rA = rel_lds[irA][lane];
            const float  rB = rel_lds[irB][lane];
            const float2 cA = rv_rs[irA];
            const float2 cB = rv_rs[irB];

            float eA = __expf(hA * cA.x);
            float eB = __expf(hB * cB.x);
            float dA = red32p(eA);
            float dB = red32p(eB);
            float rtA = red64p(rA * tA);
            float rtB = red64p(rB * tB);

            o0 = fmaf(tA, eA * __builtin_amdgcn_rcpf(dA), o0);
            o1 = fmaf(tB, eB * __builtin_amdgcn_rcpf(dB), o1);

            float zA = hA * rtA, zB = hB * rtB;
            kge_acc += __builtin_amdgcn_rcpf(1.f + __expf(-zA));
            kge_acc += __builtin_amdgcn_rcpf(1.f + __expf(-zB));

            l2_acc = fmaf(hA, hA, l2_acc);
            l2_acc = fmaf(tA, tA, l2_acc);
            l2_acc = fmaf(hB, hB, l2_acc);
            l2_acc = fmaf(tB, tB, l2_acc);
            l2r_acc += cA.y + cB.y;
        }

        // attention logits: a_g = relu(dot(o_g, u_hop))
        const float uh = u[hop * DIM + lane];
        float a0 = fmaxf(red64p(o0 * uh), 0.f);
        float a1 = fmaxf(red64p(o1 * uh), 0.f);
        if (lane == 0) { a_lds[g0] = a0; a_lds[g1] = a1; }
        o_lds[g0][lane] = o0;
        o_lds[g1][lane] = o1;
        __syncthreads();

        if (wid == 0) {
            float amax = -1e30f;
#pragma unroll
            for (int gg = 0; gg < G; ++gg) amax = fmaxf(amax, a_lds[gg]);
            float wexp[G]; float wsum = 0.f;
#pragma unroll
            for (int gg = 0; gg < G; ++gg) { wexp[gg] = __expf(a_lds[gg] - amax); wsum += wexp[gg]; }
            float inv = 1.f / wsum;
            float oh = 0.f;
#pragma unroll
            for (int gg = 0; gg < G; ++gg) oh = fmaf(o_lds[gg][lane], wexp[gg] * inv, oh);
            y0 += oh;
            if (hop == 1) x1 = v + oh;
        }
        __syncthreads();   // before next hop overwrites a_lds / o_lds
    }

    // block-level scalar reductions
    float kk = red64p(kge_acc);
    float ll = red64p(l2_acc);
    if (lane == 0) { red_k[wid] = kk; red_l[wid] = ll + l2r_acc; }
    if (wid == 0) y_lds[lane] = y0;
    __syncthreads();

    if (tid == 0) {
        float sk = 0.f, sl = 0.f;
#pragma unroll
        for (int gg = 0; gg < 8; ++gg) { sk += red_k[gg]; sl += red_l[gg]; }
        atomicAdd(&acc[1], (double)sk);
        atomicAdd(&acc[2], (double)sl);
    }

    if (wid == 0) {
        // z_d = sum_e Tm[d][e] * y[e]; score = dot(x1, Tm @ y)
        float z = 0.f;
#pragma unroll
        for (int e = 0; e < DIM; ++e) z = fmaf(Tm[lane * DIM + e], y_lds[e], z);
        float score = red64p(x1 * z);
        float nv    = ent[(size_t)neg_items[b] * DIM + lane];
        float nsc   = red64p(nv * y0);
        if (lane == 0) {
            float diff = score - nsc;
            float ls = fminf(diff, 0.f) - log1pf(__expf(-fabsf(diff)));
            atomicAdd(&acc[0], (double)ls);
        }
    }
}

__global__ void kgan_finalize(const double* __restrict__ acc, float* __restrict__ out) {
    double mf  = -acc[0] / (double)BATCH;
    double kge = acc[1] / ((double)BATCH * G * NMEM * DIM);   // sum of per-hop means
    double l2  = acc[2];
    out[0] = (float)(mf - 0.01 * kge + 1e-5 * l2);
}

extern "C" void kernel_launch(void* const* d_in, const int* in_sizes, int n_in,
                              void* d_out, int out_size, void* d_ws, size_t ws_size,
                              hipStream_t stream) {
    const int*   pos_items = (const int*)d_in[0];
    const int*   neg_items = (const int*)d_in[1];
    const int*   mem_h     = (const int*)d_in[2];
    const int*   mem_r     = (const int*)d_in[3];
    const int*   mem_t     = (const int*)d_in[4];
    const float* ent       = (const float*)d_in[5];
    const float* rel       = (const float*)d_in[6];
    const float* Tm        = (const float*)d_in[7];
    const float* attn_w1   = (const float*)d_in[8];
    const float* attn_w2   = (const float*)d_in[9];

    double* acc = (double*)d_ws;                     // 4 doubles
    float*  u   = (float*)((char*)d_ws + 64);        // 2*64 floats

    kgan_prep<<<1, 128, 0, stream>>>(attn_w1, attn_w2, u, acc);
    kgan_main<<<BATCH, 512, 0, stream>>>(pos_items, neg_items, mem_h, mem_r, mem_t,
                                         ent, rel, Tm, u, acc);
    kgan_finalize<<<1, 1, 0, stream>>>(acc, (float*)d_out);
}